// Round 10
// baseline (38.526 us; speedup 1.0000x reference)
//
#include <hip/hip_runtime.h>
#include <hip/hip_bf16.h>

constexpr int HIDDEN = 256;
constexpr int BAG    = 32;
constexpr int FEAT   = 41025;   // FEATURE_COUNT + 1 (includes zero pad row)
constexpr int NJ     = 64;      // P columns: [0:32]=us-proj, [32:64]=them-proj
constexpr int NTILES = (FEAT + 63) / 64;   // 642

using bf16x8 = __attribute__((ext_vector_type(8))) short;
using f32x4  = __attribute__((ext_vector_type(4))) float;

typedef const __attribute__((address_space(1))) unsigned int* gas_u32;
typedef __attribute__((address_space(3))) unsigned int*       las_u32;

__device__ inline void load_lds16(const float* g, float* l) {
    // async global->LDS, 16B/lane; LDS dest = uniform base + lane*16
    __builtin_amdgcn_global_load_lds((gas_u32)(const void*)g,
                                     (las_u32)(void*)l, 16, 0, 0);
}
__device__ inline short f2bf(float f) {            // fp32 -> bf16 RNE
    __hip_bfloat16 h = __float2bfloat16(f);
    return __builtin_bit_cast(short, h);
}
__device__ inline bf16x8 pack8(float4 a, float4 b) {
    bf16x8 r;
    r[0]=f2bf(a.x); r[1]=f2bf(a.y); r[2]=f2bf(a.z); r[3]=f2bf(a.w);
    r[4]=f2bf(b.x); r[5]=f2bf(b.y); r[6]=f2bf(b.z); r[7]=f2bf(b.w);
    return r;
}

// ---------- k0: P = emb @ W2d via bf16 MFMA, m97-regime staging ----------
// BK=64 fp32 chunks, 2x16KB LDS double-buffer via global_load_lds (linear dest,
// XOR quad-swizzled global SOURCE; reads use same XOR -> conflict-free).
// B (fc1_w as W2d[64 cols][256 k]) bounced through LDS once -> breg[4][8] VGPRs.
__global__ __launch_bounds__(256, 2) void k0_project_mfma(
    const float* __restrict__ emb,
    const float* __restrict__ fc1_w,
    float*       __restrict__ P)
{
    __shared__ float buf[2][64 * 64];   // two 16 KB chunk buffers

    const int tid  = threadIdx.x;
    const int lane = tid & 63, wave = tid >> 6;
    const int g = lane >> 4, ml = lane & 15;
    const int mw = wave * 16;           // wave's 16 rows (A) / staging rows
    const int f0 = blockIdx.x * 64;
    const int lhi = lane >> 4;          // row sub-index within one staging inst
    const int lql = lane & 15;          // quad sub-index within one staging inst

    // ---- B prologue: 4 chunks bounced through buf[0/1] -> breg
    bf16x8 breg[4][8];
#pragma unroll
    for (int kc2 = 0; kc2 < 2; ++kc2) {
#pragma unroll
        for (int h = 0; h < 2; ++h) {
            const int kc = kc2 * 2 + h;
#pragma unroll
            for (int i = 0; i < 4; ++i) {
                const int row0 = mw + i * 4;
                const int j = row0 + lhi;          // W2d column this lane stages
                const float* gp = fc1_w + (size_t)(j & 31) * 512 + ((j >> 5) << 8)
                                 + (kc << 6) + ((lql ^ (j & 7)) << 2);
                load_lds16(gp, &buf[h][row0 * 64]);
            }
        }
        __syncthreads();
#pragma unroll
        for (int h = 0; h < 2; ++h) {
            const int kc = kc2 * 2 + h;
#pragma unroll
            for (int nt = 0; nt < 4; ++nt) {
                const int rb = nt * 16 + ml, sw = ml & 7;
                const float* rp = &buf[h][rb * 64];
#pragma unroll
                for (int ktl = 0; ktl < 2; ++ktl) {
                    const int q0 = ktl * 8 + g * 2;
                    const float4 x0 = *reinterpret_cast<const float4*>(rp + ((q0 ^ sw) << 2));
                    const float4 x1 = *reinterpret_cast<const float4*>(rp + (((q0 + 1) ^ sw) << 2));
                    breg[nt][kc * 2 + ktl] = pack8(x0, x1);
                }
            }
        }
        __syncthreads();                 // buffers free for reuse
    }

    // ---- A: 4 chunks, double-buffered; stage(next) issued BEFORE compute(cur)
    auto stageA = [&](int kc, int bsel) {
#pragma unroll
        for (int i = 0; i < 4; ++i) {
            const int row0 = mw + i * 4;
            const int r = row0 + lhi;
            int grow = f0 + r; if (grow >= FEAT) grow = FEAT - 1;  // clamp, rows not stored
            const float* gp = emb + (size_t)grow * 256 + (kc << 6)
                             + ((lql ^ (r & 7)) << 2);
            load_lds16(gp, &buf[bsel][row0 * 64]);
        }
    };
    stageA(0, 0);
    __syncthreads();

    f32x4 acc[4] = {{0.f,0.f,0.f,0.f},{0.f,0.f,0.f,0.f},
                    {0.f,0.f,0.f,0.f},{0.f,0.f,0.f,0.f}};
#pragma unroll
    for (int kc = 0; kc < 4; ++kc) {
        if (kc < 3) stageA(kc + 1, (kc + 1) & 1);   // async under compute
        const int sw = ml & 7;
        const float* rp = &buf[kc & 1][(mw + ml) * 64];
#pragma unroll
        for (int ktl = 0; ktl < 2; ++ktl) {
            const int q0 = ktl * 8 + g * 2;
            const float4 x0 = *reinterpret_cast<const float4*>(rp + ((q0 ^ sw) << 2));
            const float4 x1 = *reinterpret_cast<const float4*>(rp + (((q0 + 1) ^ sw) << 2));
            const bf16x8 af = pack8(x0, x1);
            const int kt = kc * 2 + ktl;
#pragma unroll
            for (int nt = 0; nt < 4; ++nt)
                acc[nt] = __builtin_amdgcn_mfma_f32_16x16x32_bf16(af, breg[nt][kt],
                                                                  acc[nt], 0, 0, 0);
        }
        if (kc < 3) __syncthreads();
    }

    // D layout: row = g*4 + r, col = ml (verified C/D mapping)
#pragma unroll
    for (int nt = 0; nt < 4; ++nt) {
#pragma unroll
        for (int r = 0; r < 4; ++r) {
            const int f = f0 + mw + g * 4 + r;
            if (f < FEAT)
                P[(size_t)f * NJ + nt * 16 + ml] = acc[nt][r];
        }
    }
}

// ---------- k1: gather P rows (128 B each) + fused MLP. One wave per batch row.
__global__ __launch_bounds__(256) void k1_gather_mlp(
    const int*   __restrict__ us,
    const int*   __restrict__ them,
    const float* __restrict__ P,
    const float* __restrict__ b1,
    const float* __restrict__ w2, const float* __restrict__ b2,
    const float* __restrict__ w3, const float* __restrict__ b3,
    float*       __restrict__ out)
{
    __shared__ float w2_lds[32][33];
    __shared__ float y1_lds[4][32];

    const int tid  = threadIdx.x;
    const int wave = tid >> 6;
    const int lane = tid & 63;

    for (int k = tid; k < 32 * 32; k += 256)
        w2_lds[k >> 5][k & 31] = w2[k];
    __syncthreads();

    const int row = blockIdx.x * 4 + wave;
    int idx;
    {
        const int* up = us   + (size_t)row * BAG;
        const int* tp = them + (size_t)row * BAG;
        idx = (lane < BAG) ? up[lane] : tp[lane - BAG];
    }

    float acc = 0.f;
    const int srcbase = lane & 32;
#pragma unroll
    for (int i = 0; i < BAG; ++i) {
        const int f = __shfl(idx, srcbase + i);
        acc += P[(size_t)f * NJ + lane];
    }
    acc += __shfl_xor(acc, 32);

    if (lane < 32)
        y1_lds[wave][lane] = fminf(fmaxf(acc + b1[lane], 0.f), 1.f);
    __syncthreads();

    float r3 = 0.f;
    if (lane < 32) {
        float s = b2[lane];
#pragma unroll
        for (int k = 0; k < 32; ++k) s += y1_lds[wave][k] * w2_lds[lane][k];
        r3 = fminf(fmaxf(s, 0.f), 1.f) * w3[lane];
    }
    r3 += __shfl_xor(r3, 16); r3 += __shfl_xor(r3, 8); r3 += __shfl_xor(r3, 4);
    r3 += __shfl_xor(r3, 2);  r3 += __shfl_xor(r3, 1);
    if (lane == 0) out[row] = tanhf(r3 + b3[0]);
}

// ---------- fallback: R0 monolithic kernel (if ws too small) ----------
__global__ __launch_bounds__(256) void nnue_fused(
    const int*   __restrict__ us,
    const int*   __restrict__ them,
    const float* __restrict__ emb,
    const float* __restrict__ w1, const float* __restrict__ b1,
    const float* __restrict__ w2, const float* __restrict__ b2,
    const float* __restrict__ w3, const float* __restrict__ b3,
    float*       __restrict__ out)
{
    __shared__ float x_lds[4][2 * HIDDEN];
    __shared__ float y1_lds[4][32];
    __shared__ float y2_lds[4][32];

    const int tid  = threadIdx.x;
    const int wave = tid >> 6;
    const int lane = tid & 63;
    const int row  = blockIdx.x * 4 + wave;

    int myidx;
    {
        const int* up = us   + (size_t)row * BAG;
        const int* tp = them + (size_t)row * BAG;
        myidx = (lane < BAG) ? up[lane] : tp[lane - BAG];
    }
    const float4* emb4 = reinterpret_cast<const float4*>(emb);
    float4 accU = make_float4(0.f, 0.f, 0.f, 0.f);
    float4 accT = make_float4(0.f, 0.f, 0.f, 0.f);
#pragma unroll
    for (int i = 0; i < BAG; ++i) {
        const int iu = __shfl(myidx, i);
        const int it = __shfl(myidx, BAG + i);
        const float4 vu = emb4[(size_t)iu * (HIDDEN / 4) + lane];
        const float4 vt = emb4[(size_t)it * (HIDDEN / 4) + lane];
        accU.x += vu.x; accU.y += vu.y; accU.z += vu.z; accU.w += vu.w;
        accT.x += vt.x; accT.y += vt.y; accT.z += vt.z; accT.w += vt.w;
    }
    {
        float4* xv = reinterpret_cast<float4*>(&x_lds[wave][0]);
        xv[lane]      = accU;
        xv[64 + lane] = accT;
    }
    __syncthreads();
    {
        const int r    = tid >> 6;
        const int sub  = tid & 63;
        const int j    = sub >> 1;
        const int half = sub & 1;
        const float4* xr = reinterpret_cast<const float4*>(&x_lds[r][0]) + half * 64;
        const float4* wr = reinterpret_cast<const float4*>(w1 + (size_t)j * (2 * HIDDEN)) + half * 64;
        float s = 0.f;
#pragma unroll 8
        for (int k = 0; k < 64; ++k) {
            const float4 xk = xr[k];
            const float4 wk = wr[k];
            s += xk.x * wk.x + xk.y * wk.y + xk.z * wk.z + xk.w * wk.w;
        }
        s += __shfl_xor(s, 1);
        if (half == 0) { s += b1[j]; y1_lds[r][j] = fminf(fmaxf(s, 0.f), 1.f); }
    }
    __syncthreads();
    if (tid < 4 * 32) {
        const int r = tid >> 5;
        const int j = tid & 31;
        const float* wr = w2 + j * 32;
        float s = b2[j];
#pragma unroll
        for (int k = 0; k < 32; ++k) s += y1_lds[r][k] * wr[k];
        y2_lds[r][j] = fminf(fmaxf(s, 0.f), 1.f);
    }
    __syncthreads();
    if (tid < 4) {
        const int r = tid;
        float s = b3[0];
#pragma unroll
        for (int k = 0; k < 32; ++k) s += y2_lds[r][k] * w3[k];
        out[blockIdx.x * 4 + r] = tanhf(s);
    }
}

extern "C" void kernel_launch(void* const* d_in, const int* in_sizes, int n_in,
                              void* d_out, int out_size, void* d_ws, size_t ws_size,
                              hipStream_t stream) {
    const int*   us   = (const int*)  d_in[0];
    const int*   them = (const int*)  d_in[1];
    const float* emb  = (const float*)d_in[2];
    const float* w1   = (const float*)d_in[3];
    const float* b1   = (const float*)d_in[4];
    const float* w2   = (const float*)d_in[5];
    const float* b2   = (const float*)d_in[6];
    const float* w3   = (const float*)d_in[7];
    const float* b3   = (const float*)d_in[8];
    float* out = (float*)d_out;

    const int batch = in_sizes[0] / BAG;                       // 8192
    const size_t p_bytes = (size_t)FEAT * NJ * sizeof(float);  // 10.5 MB

    if (ws_size >= p_bytes) {
        float* P = (float*)d_ws;
        // DIAGNOSTIC (this round only): extra k1 on stale/poisoned P, output
        // overwritten by the real k1 below. total = k0 + 2*k1 -> separates
        // k0 vs k1 cost. Deterministic: reads ws state from previous call.
        k1_gather_mlp<<<batch / 4, 256, 0, stream>>>(us, them, P,
                                                     b1, w2, b2, w3, b3, out);
        k0_project_mfma<<<NTILES, 256, 0, stream>>>(emb, w1, P);
        k1_gather_mlp<<<batch / 4, 256, 0, stream>>>(us, them, P,
                                                     b1, w2, b2, w3, b3, out);
    } else {
        nnue_fused<<<(batch + 3) / 4, 256, 0, stream>>>(us, them, emb,
                                                        w1, b1, w2, b2, w3, b3, out);
    }
}